// Round 1
// baseline (919.034 us; speedup 1.0000x reference)
//
#include <hip/hip_runtime.h>
#include <cstdint>
#include <cstddef>

typedef __bf16 bf16;
typedef __attribute__((ext_vector_type(8))) __bf16 bf16x8;
typedef __attribute__((ext_vector_type(4))) float f32x4;

#define BM 128
#define BN 128
#define BK 64

// fp32 -> bf16 round-to-nearest-even (unbiased; truncation would bias the
// K=4096 dot by ~1.0 and fail the 0.7 threshold).
__device__ __forceinline__ unsigned bf16_rne(float f) {
  unsigned u = __float_as_uint(f);
  unsigned r = 0x7FFFu + ((u >> 16) & 1u);
  return ((u + r) >> 16) & 0xFFFFu;
}

__device__ __forceinline__ unsigned pack2(float a, float b) {
  return bf16_rne(a) | (bf16_rne(b) << 16);
}

// ---------------- Phase 1a: x fp32 -> bf16 ----------------
__global__ void cvt_x_kernel(const float* __restrict__ x, uint4* __restrict__ xb, int n8) {
  int i = blockIdx.x * blockDim.x + threadIdx.x;
  if (i >= n8) return;
  const float4* p = (const float4*)x + (size_t)i * 2;
  float4 a = p[0], b = p[1];
  uint4 o;
  o.x = pack2(a.x, a.y);
  o.y = pack2(a.z, a.w);
  o.z = pack2(b.x, b.y);
  o.w = pack2(b.z, b.w);
  xb[i] = o;
}

// ---------------- Phase 1b: dequant qweight -> bf16 W [N][K] ----------------
__global__ void dequant_w_kernel(const int* __restrict__ q,
                                 const float* __restrict__ scale,
                                 const int* __restrict__ zp,
                                 uint4* __restrict__ w,
                                 int K, int G) {
  int col8 = blockIdx.x * blockDim.x + threadIdx.x;  // 8-element chunk in row
  int o = blockIdx.y;
  int kcol = col8 * 8;
  if (kcol >= K) return;
  int g = kcol >> 7;  // GROUP_SIZE = 128
  float s = scale[(size_t)o * G + g];
  float z = (float)zp[(size_t)o * G + g];
  const int4* src = (const int4*)(q + (size_t)o * K + kcol);
  int4 q0 = src[0], q1 = src[1];
  uint4 out;
  out.x = pack2(((float)q0.x - z) * s, ((float)q0.y - z) * s);
  out.y = pack2(((float)q0.z - z) * s, ((float)q0.w - z) * s);
  out.z = pack2(((float)q1.x - z) * s, ((float)q1.y - z) * s);
  out.w = pack2(((float)q1.z - z) * s, ((float)q1.w - z) * s);
  w[((size_t)o * K + kcol) >> 3] = out;
}

// ---------------- Phase 2: bf16 GEMM, m97 structure ----------------
typedef __attribute__((address_space(1))) void gas_void;
typedef __attribute__((address_space(3))) void las_void;

__device__ __forceinline__ void load_lds16(const void* g, void* l) {
  // async global->LDS, 16B/lane; LDS dest = wave-uniform base + lane*16
  __builtin_amdgcn_global_load_lds((gas_void*)g, (las_void*)l, 16, 0, 0);
}

// LDS layout: 16B chunk (row r, kq) stored at slot r*8 + (kq ^ (r&7)).
// - staging: slot s -> r = s>>3, source kq = (s&7) ^ (r&7); contiguous lane order. ✓
// - fragment ds_read_b128: per quad, 16 lanes hit each 4-bank group exactly
//   twice -> 2-way aliasing = free (m136).
__global__ __launch_bounds__(256) void gemm_bf16_kernel(
    const bf16* __restrict__ A,   // [M][K] bf16
    const bf16* __restrict__ Bw,  // [N][K] bf16 (W, row-major over K)
    const float* __restrict__ bias,
    float* __restrict__ C,        // [M][N] fp32
    int M, int N, int K) {
  __shared__ __align__(16) bf16 Alds[BM * BK];
  __shared__ __align__(16) bf16 Blds[BN * BK];
  const int tid  = threadIdx.x;
  const int wave = tid >> 6;
  const int lane = tid & 63;
  const int quad = lane >> 4;
  const int l16  = lane & 15;
  const int bm = blockIdx.y * BM;
  const int bn = blockIdx.x * BN;
  const int wm = (wave & 1) * 64;
  const int wn = (wave >> 1) * 64;

  f32x4 acc[4][4];
#pragma unroll
  for (int i = 0; i < 4; ++i)
#pragma unroll
    for (int j = 0; j < 4; ++j)
      acc[i][j] = (f32x4){0.f, 0.f, 0.f, 0.f};

  for (int kt = 0; kt < K; kt += BK) {
#pragma unroll
    for (int t = 0; t < 4; ++t) {
      int s0 = (wave * 4 + t) * 64;   // wave-uniform LDS slot base
      int s  = s0 + lane;
      int m  = s >> 3;
      int kq = (s & 7) ^ (m & 7);
      const bf16* ga = A  + (size_t)(bm + m) * K + kt + kq * 8;
      const bf16* gb = Bw + (size_t)(bn + m) * K + kt + kq * 8;
      load_lds16(ga, &Alds[s0 * 8]);
      load_lds16(gb, &Blds[s0 * 8]);
    }
    __syncthreads();

#pragma unroll
    for (int ks = 0; ks < 2; ++ks) {
      bf16x8 af[4], bfr[4];
#pragma unroll
      for (int tm = 0; tm < 4; ++tm) {
        int m  = wm + tm * 16 + l16;
        int kq = ks * 4 + quad;
        af[tm] = *(const bf16x8*)&Alds[(m * 8 + (kq ^ (m & 7))) * 8];
      }
#pragma unroll
      for (int tn = 0; tn < 4; ++tn) {
        int n  = wn + tn * 16 + l16;
        int kq = ks * 4 + quad;
        bfr[tn] = *(const bf16x8*)&Blds[(n * 8 + (kq ^ (n & 7))) * 8];
      }
#pragma unroll
      for (int tm = 0; tm < 4; ++tm)
#pragma unroll
        for (int tn = 0; tn < 4; ++tn)
          acc[tm][tn] = __builtin_amdgcn_mfma_f32_16x16x32_bf16(
              af[tm], bfr[tn], acc[tm][tn], 0, 0, 0);
    }
    __syncthreads();
  }

  // Epilogue: D row = quad*4 + v, col = lane&15 (m89-verified mapping)
#pragma unroll
  for (int tn = 0; tn < 4; ++tn) {
    int col = bn + wn + tn * 16 + l16;
    float bv = bias[col];
#pragma unroll
    for (int tm = 0; tm < 4; ++tm) {
      int row0 = bm + wm + tm * 16 + quad * 4;
#pragma unroll
      for (int v = 0; v < 4; ++v)
        C[(size_t)(row0 + v) * N + col] = acc[tm][tn][v] + bv;
    }
  }
}

// ---------------- Fallback: fused dequant GEMM (if ws too small) ----------------
__global__ __launch_bounds__(256) void gemm_fused_kernel(
    const float* __restrict__ X,  // [M][K] fp32
    const int* __restrict__ Q,    // [N][K] int32
    const float* __restrict__ scale,
    const int* __restrict__ zp,
    const float* __restrict__ bias,
    float* __restrict__ C,
    int M, int N, int K, int G) {
  __shared__ __align__(16) bf16 Alds[BM * BK];
  __shared__ __align__(16) bf16 Blds[BN * BK];
  const int tid  = threadIdx.x;
  const int wave = tid >> 6;
  const int lane = tid & 63;
  const int quad = lane >> 4;
  const int l16  = lane & 15;
  const int bm = blockIdx.y * BM;
  const int bn = blockIdx.x * BN;
  const int wm = (wave & 1) * 64;
  const int wn = (wave >> 1) * 64;

  f32x4 acc[4][4];
#pragma unroll
  for (int i = 0; i < 4; ++i)
#pragma unroll
    for (int j = 0; j < 4; ++j)
      acc[i][j] = (f32x4){0.f, 0.f, 0.f, 0.f};

  for (int kt = 0; kt < K; kt += BK) {
    // A tile: cvt fp32->bf16 into swizzled chunks
#pragma unroll
    for (int i = 0; i < 4; ++i) {
      int c = tid + i * 256;
      int m = c >> 3;
      int kq = (c & 7) ^ (m & 7);
      const float* src = X + (size_t)(bm + m) * K + kt + kq * 8;
      float4 v0 = *(const float4*)src;
      float4 v1 = *(const float4*)(src + 4);
      uint4 p;
      p.x = pack2(v0.x, v0.y);
      p.y = pack2(v0.z, v0.w);
      p.z = pack2(v1.x, v1.y);
      p.w = pack2(v1.z, v1.w);
      *(uint4*)&Alds[c * 8] = p;
    }
    // B tile: dequant into swizzled chunks
#pragma unroll
    for (int i = 0; i < 4; ++i) {
      int c = tid + i * 256;
      int n = c >> 3;
      int kq = (c & 7) ^ (n & 7);
      int kcol = kt + kq * 8;
      size_t row = (size_t)(bn + n);
      int g = kcol >> 7;
      float s = scale[row * G + g];
      float z = (float)zp[row * G + g];
      const int* src = Q + row * K + kcol;
      int4 q0 = *(const int4*)src;
      int4 q1 = *(const int4*)(src + 4);
      uint4 p;
      p.x = pack2(((float)q0.x - z) * s, ((float)q0.y - z) * s);
      p.y = pack2(((float)q0.z - z) * s, ((float)q0.w - z) * s);
      p.z = pack2(((float)q1.x - z) * s, ((float)q1.y - z) * s);
      p.w = pack2(((float)q1.z - z) * s, ((float)q1.w - z) * s);
      *(uint4*)&Blds[c * 8] = p;
    }
    __syncthreads();

#pragma unroll
    for (int ks = 0; ks < 2; ++ks) {
      bf16x8 af[4], bfr[4];
#pragma unroll
      for (int tm = 0; tm < 4; ++tm) {
        int m  = wm + tm * 16 + l16;
        int kq = ks * 4 + quad;
        af[tm] = *(const bf16x8*)&Alds[(m * 8 + (kq ^ (m & 7))) * 8];
      }
#pragma unroll
      for (int tn = 0; tn < 4; ++tn) {
        int n  = wn + tn * 16 + l16;
        int kq = ks * 4 + quad;
        bfr[tn] = *(const bf16x8*)&Blds[(n * 8 + (kq ^ (n & 7))) * 8];
      }
#pragma unroll
      for (int tm = 0; tm < 4; ++tm)
#pragma unroll
        for (int tn = 0; tn < 4; ++tn)
          acc[tm][tn] = __builtin_amdgcn_mfma_f32_16x16x32_bf16(
              af[tm], bfr[tn], acc[tm][tn], 0, 0, 0);
    }
    __syncthreads();
  }

#pragma unroll
  for (int tn = 0; tn < 4; ++tn) {
    int col = bn + wn + tn * 16 + l16;
    float bv = bias[col];
#pragma unroll
    for (int tm = 0; tm < 4; ++tm) {
      int row0 = bm + wm + tm * 16 + quad * 4;
#pragma unroll
      for (int v = 0; v < 4; ++v)
        C[(size_t)(row0 + v) * N + col] = acc[tm][tn][v] + bv;
    }
  }
}

extern "C" void kernel_launch(void* const* d_in, const int* in_sizes, int n_in,
                              void* d_out, int out_size, void* d_ws, size_t ws_size,
                              hipStream_t stream) {
  const float* x     = (const float*)d_in[0];
  const int*   qw    = (const int*)d_in[1];
  const float* scale = (const float*)d_in[2];
  const int*   zp    = (const int*)d_in[3];
  const float* bias  = (const float*)d_in[4];
  float* out = (float*)d_out;

  const int O = in_sizes[4];                 // 11008
  const int I = (int)(in_sizes[1] / O);      // 4096
  const int M = (int)(in_sizes[0] / I);      // 4096 (= B*S)
  const int G = in_sizes[2] / O;             // 32
  const int K = I, N = O;

  const size_t xbytes = (size_t)M * K * sizeof(bf16);
  const size_t wbytes = (size_t)N * K * sizeof(bf16);

  dim3 gemm_grid((unsigned)(N / BN), (unsigned)(M / BM));

  if (ws_size >= xbytes + wbytes) {
    bf16* xb = (bf16*)d_ws;
    bf16* wb = (bf16*)((char*)d_ws + xbytes);

    int n8 = (int)((size_t)M * K / 8);
    cvt_x_kernel<<<(n8 + 255) / 256, 256, 0, stream>>>(x, (uint4*)xb, n8);

    dim3 dq_grid((unsigned)(K / (8 * 256)), (unsigned)N);
    dequant_w_kernel<<<dq_grid, 256, 0, stream>>>(qw, scale, zp, (uint4*)wb, K, G);

    gemm_bf16_kernel<<<gemm_grid, 256, 0, stream>>>(xb, wb, bias, out, M, N, K);
  } else {
    gemm_fused_kernel<<<gemm_grid, 256, 0, stream>>>(x, qw, scale, zp, bias, out,
                                                     M, N, K, G);
  }
}

// Round 2
// 801.901 us; speedup vs baseline: 1.1461x; 1.1461x over previous
//
#include <hip/hip_runtime.h>
#include <cstdint>
#include <cstddef>

typedef __bf16 bf16;
typedef __attribute__((ext_vector_type(8))) __bf16 bf16x8;
typedef __attribute__((ext_vector_type(4))) float f32x4;

#define BM 128
#define BN 128
#define BK 64
#define GROUP_M 16

// fp32 -> bf16 round-to-nearest-even (unbiased; truncation would bias the
// K=4096 dot by ~1.0 and fail the 0.7 threshold).
__device__ __forceinline__ unsigned bf16_rne(float f) {
  unsigned u = __float_as_uint(f);
  unsigned r = 0x7FFFu + ((u >> 16) & 1u);
  return ((u + r) >> 16) & 0xFFFFu;
}

__device__ __forceinline__ unsigned pack2(float a, float b) {
  return bf16_rne(a) | (bf16_rne(b) << 16);
}

// ---------------- Phase 1 (merged): x fp32->bf16 AND dequant W->bf16 ----------
// blocks [0, nx)        : convert x (each thread: 8 floats -> 8 bf16)
// blocks [nx, nx + nw)  : dequant qweight (each thread: 8 int32 -> 8 bf16)
__global__ void prep_kernel(const float* __restrict__ x, uint4* __restrict__ xb,
                            int nx,
                            const int* __restrict__ q,
                            const float* __restrict__ scale,
                            const int* __restrict__ zp,
                            uint4* __restrict__ w, int K, int G) {
  int b = blockIdx.x;
  int tid = threadIdx.x;
  if (b < nx) {
    size_t i = (size_t)b * 256 + tid;   // 8-float chunk index
    const float4* p = (const float4*)x + i * 2;
    float4 a0 = p[0], a1 = p[1];
    uint4 o;
    o.x = pack2(a0.x, a0.y);
    o.y = pack2(a0.z, a0.w);
    o.z = pack2(a1.x, a1.y);
    o.w = pack2(a1.z, a1.w);
    xb[i] = o;
  } else {
    size_t c = (size_t)(b - nx) * 256 + tid;   // 8-elem chunk over [N*K/8)
    int kper8 = K >> 3;
    int o = (int)(c / kper8);
    int kcol = ((int)(c % kper8)) << 3;
    int g = kcol >> 7;  // GROUP_SIZE = 128
    float s = scale[(size_t)o * G + g];
    float z = (float)zp[(size_t)o * G + g];
    const int4* src = (const int4*)(q + (size_t)o * K + kcol);
    int4 q0 = src[0], q1 = src[1];
    uint4 out;
    out.x = pack2(((float)q0.x - z) * s, ((float)q0.y - z) * s);
    out.y = pack2(((float)q0.z - z) * s, ((float)q0.w - z) * s);
    out.z = pack2(((float)q1.x - z) * s, ((float)q1.y - z) * s);
    out.w = pack2(((float)q1.z - z) * s, ((float)q1.w - z) * s);
    w[c] = out;
  }
}

// ---------------- Phase 2: bf16 GEMM, m97 structure + grouped-m swizzle ------
typedef __attribute__((address_space(1))) void gas_void;
typedef __attribute__((address_space(3))) void las_void;

__device__ __forceinline__ void load_lds16(const void* g, void* l) {
  // async global->LDS, 16B/lane; LDS dest = wave-uniform base + lane*16
  __builtin_amdgcn_global_load_lds((gas_void*)g, (las_void*)l, 16, 0, 0);
}

// LDS layout: 16B chunk (row r, kq) stored at slot r*8 + (kq ^ (r&7)).
// - staging: slot s -> r = s>>3, source kq = (s&7) ^ (r&7); contiguous lane order.
// - fragment ds_read_b128: 2-way bank aliasing max = free (m136). Verified R1:
//   SQ_LDS_BANK_CONFLICT == 0.
__global__ __launch_bounds__(256) void gemm_bf16_kernel(
    const bf16* __restrict__ A,   // [M][K] bf16
    const bf16* __restrict__ Bw,  // [N][K] bf16 (W, row-major over K)
    const float* __restrict__ bias,
    float* __restrict__ C,        // [M][N] fp32
    int M, int N, int K) {
  __shared__ __align__(16) bf16 Alds[BM * BK];
  __shared__ __align__(16) bf16 Blds[BN * BK];
  const int tid  = threadIdx.x;
  const int wave = tid >> 6;
  const int lane = tid & 63;
  const int quad = lane >> 4;
  const int l16  = lane & 15;

  // Grouped-m swizzle: consecutive blocks walk m within a GROUP_M-panel first,
  // then n. Concurrent window = one A-panel (GROUP_M MB) + W n-slices with
  // 16-block reuse distance -> L2/LLC hits instead of 1.5 GB of HBM fetch (R1).
  const int nbm = M / BM;
  const int nbn = N / BN;
  int flat = blockIdx.x;
  int per_group = GROUP_M * nbn;
  int gid = flat / per_group;
  int rem = flat - gid * per_group;
  int gm = nbm - gid * GROUP_M;
  if (gm > GROUP_M) gm = GROUP_M;
  const int bm = (gid * GROUP_M + (rem % gm)) * BM;
  const int bn = (rem / gm) * BN;

  const int wm = (wave & 1) * 64;
  const int wn = (wave >> 1) * 64;

  f32x4 acc[4][4];
#pragma unroll
  for (int i = 0; i < 4; ++i)
#pragma unroll
    for (int j = 0; j < 4; ++j)
      acc[i][j] = (f32x4){0.f, 0.f, 0.f, 0.f};

  for (int kt = 0; kt < K; kt += BK) {
#pragma unroll
    for (int t = 0; t < 4; ++t) {
      int s0 = (wave * 4 + t) * 64;   // wave-uniform LDS slot base
      int s  = s0 + lane;
      int m  = s >> 3;
      int kq = (s & 7) ^ (m & 7);
      const bf16* ga = A  + (size_t)(bm + m) * K + kt + kq * 8;
      const bf16* gb = Bw + (size_t)(bn + m) * K + kt + kq * 8;
      load_lds16(ga, &Alds[s0 * 8]);
      load_lds16(gb, &Blds[s0 * 8]);
    }
    __syncthreads();

#pragma unroll
    for (int ks = 0; ks < 2; ++ks) {
      bf16x8 af[4], bfr[4];
#pragma unroll
      for (int tm = 0; tm < 4; ++tm) {
        int m  = wm + tm * 16 + l16;
        int kq = ks * 4 + quad;
        af[tm] = *(const bf16x8*)&Alds[(m * 8 + (kq ^ (m & 7))) * 8];
      }
#pragma unroll
      for (int tn = 0; tn < 4; ++tn) {
        int n  = wn + tn * 16 + l16;
        int kq = ks * 4 + quad;
        bfr[tn] = *(const bf16x8*)&Blds[(n * 8 + (kq ^ (n & 7))) * 8];
      }
#pragma unroll
      for (int tm = 0; tm < 4; ++tm)
#pragma unroll
        for (int tn = 0; tn < 4; ++tn)
          acc[tm][tn] = __builtin_amdgcn_mfma_f32_16x16x32_bf16(
              af[tm], bfr[tn], acc[tm][tn], 0, 0, 0);
    }
    __syncthreads();
  }

  // Epilogue: D row = quad*4 + v, col = lane&15 (m89-verified mapping).
  // Nontemporal stores: 180 MB of C is write-once streaming — keep it out of
  // L2 so A/W tile streams keep their residency.
#pragma unroll
  for (int tn = 0; tn < 4; ++tn) {
    int col = bn + wn + tn * 16 + l16;
    float bv = bias[col];
#pragma unroll
    for (int tm = 0; tm < 4; ++tm) {
      int row0 = bm + wm + tm * 16 + quad * 4;
#pragma unroll
      for (int v = 0; v < 4; ++v)
        __builtin_nontemporal_store(acc[tm][tn][v] + bv,
                                    &C[(size_t)(row0 + v) * N + col]);
    }
  }
}

// ---------------- Fallback: fused dequant GEMM (if ws too small) ----------------
__global__ __launch_bounds__(256) void gemm_fused_kernel(
    const float* __restrict__ X,  // [M][K] fp32
    const int* __restrict__ Q,    // [N][K] int32
    const float* __restrict__ scale,
    const int* __restrict__ zp,
    const float* __restrict__ bias,
    float* __restrict__ C,
    int M, int N, int K, int G) {
  __shared__ __align__(16) bf16 Alds[BM * BK];
  __shared__ __align__(16) bf16 Blds[BN * BK];
  const int tid  = threadIdx.x;
  const int wave = tid >> 6;
  const int lane = tid & 63;
  const int quad = lane >> 4;
  const int l16  = lane & 15;
  const int bm = blockIdx.y * BM;
  const int bn = blockIdx.x * BN;
  const int wm = (wave & 1) * 64;
  const int wn = (wave >> 1) * 64;

  f32x4 acc[4][4];
#pragma unroll
  for (int i = 0; i < 4; ++i)
#pragma unroll
    for (int j = 0; j < 4; ++j)
      acc[i][j] = (f32x4){0.f, 0.f, 0.f, 0.f};

  for (int kt = 0; kt < K; kt += BK) {
#pragma unroll
    for (int i = 0; i < 4; ++i) {
      int c = tid + i * 256;
      int m = c >> 3;
      int kq = (c & 7) ^ (m & 7);
      const float* src = X + (size_t)(bm + m) * K + kt + kq * 8;
      float4 v0 = *(const float4*)src;
      float4 v1 = *(const float4*)(src + 4);
      uint4 p;
      p.x = pack2(v0.x, v0.y);
      p.y = pack2(v0.z, v0.w);
      p.z = pack2(v1.x, v1.y);
      p.w = pack2(v1.z, v1.w);
      *(uint4*)&Alds[c * 8] = p;
    }
#pragma unroll
    for (int i = 0; i < 4; ++i) {
      int c = tid + i * 256;
      int n = c >> 3;
      int kq = (c & 7) ^ (n & 7);
      int kcol = kt + kq * 8;
      size_t row = (size_t)(bn + n);
      int g = kcol >> 7;
      float s = scale[row * G + g];
      float z = (float)zp[row * G + g];
      const int* src = Q + row * K + kcol;
      int4 q0 = *(const int4*)src;
      int4 q1 = *(const int4*)(src + 4);
      uint4 p;
      p.x = pack2(((float)q0.x - z) * s, ((float)q0.y - z) * s);
      p.y = pack2(((float)q0.z - z) * s, ((float)q0.w - z) * s);
      p.z = pack2(((float)q1.x - z) * s, ((float)q1.y - z) * s);
      p.w = pack2(((float)q1.z - z) * s, ((float)q1.w - z) * s);
      *(uint4*)&Blds[c * 8] = p;
    }
    __syncthreads();

#pragma unroll
    for (int ks = 0; ks < 2; ++ks) {
      bf16x8 af[4], bfr[4];
#pragma unroll
      for (int tm = 0; tm < 4; ++tm) {
        int m  = wm + tm * 16 + l16;
        int kq = ks * 4 + quad;
        af[tm] = *(const bf16x8*)&Alds[(m * 8 + (kq ^ (m & 7))) * 8];
      }
#pragma unroll
      for (int tn = 0; tn < 4; ++tn) {
        int n  = wn + tn * 16 + l16;
        int kq = ks * 4 + quad;
        bfr[tn] = *(const bf16x8*)&Blds[(n * 8 + (kq ^ (n & 7))) * 8];
      }
#pragma unroll
      for (int tm = 0; tm < 4; ++tm)
#pragma unroll
        for (int tn = 0; tn < 4; ++tn)
          acc[tm][tn] = __builtin_amdgcn_mfma_f32_16x16x32_bf16(
              af[tm], bfr[tn], acc[tm][tn], 0, 0, 0);
    }
    __syncthreads();
  }

#pragma unroll
  for (int tn = 0; tn < 4; ++tn) {
    int col = bn + wn + tn * 16 + l16;
    float bv = bias[col];
#pragma unroll
    for (int tm = 0; tm < 4; ++tm) {
      int row0 = bm + wm + tm * 16 + quad * 4;
#pragma unroll
      for (int v = 0; v < 4; ++v)
        C[(size_t)(row0 + v) * N + col] = acc[tm][tn][v] + bv;
    }
  }
}

extern "C" void kernel_launch(void* const* d_in, const int* in_sizes, int n_in,
                              void* d_out, int out_size, void* d_ws, size_t ws_size,
                              hipStream_t stream) {
  const float* x     = (const float*)d_in[0];
  const int*   qw    = (const int*)d_in[1];
  const float* scale = (const float*)d_in[2];
  const int*   zp    = (const int*)d_in[3];
  const float* bias  = (const float*)d_in[4];
  float* out = (float*)d_out;

  const int O = in_sizes[4];                 // 11008
  const int I = (int)(in_sizes[1] / O);      // 4096
  const int M = (int)(in_sizes[0] / I);      // 4096 (= B*S)
  const int G = in_sizes[2] / O;             // 32
  const int K = I, N = O;

  const size_t xbytes = (size_t)M * K * sizeof(bf16);
  const size_t wbytes = (size_t)N * K * sizeof(bf16);

  if (ws_size >= xbytes + wbytes) {
    bf16* xb = (bf16*)d_ws;
    bf16* wb = (bf16*)((char*)d_ws + xbytes);

    int nx = (int)((size_t)M * K / (8 * 256));
    int nw = (int)((size_t)N * K / (8 * 256));
    prep_kernel<<<nx + nw, 256, 0, stream>>>(x, (uint4*)xb, nx,
                                             qw, scale, zp, (uint4*)wb, K, G);

    int nblocks = (M / BM) * (N / BN);
    gemm_bf16_kernel<<<nblocks, 256, 0, stream>>>(xb, wb, bias, out, M, N, K);
  } else {
    dim3 gemm_grid((unsigned)(N / BN), (unsigned)(M / BM));
    gemm_fused_kernel<<<gemm_grid, 256, 0, stream>>>(x, qw, scale, zp, bias, out,
                                                     M, N, K, G);
  }
}

// Round 3
// 578.211 us; speedup vs baseline: 1.5894x; 1.3869x over previous
//
#include <hip/hip_runtime.h>
#include <cstdint>
#include <cstddef>

typedef __attribute__((ext_vector_type(4))) int i32x4;
typedef __bf16 bf16;
typedef __attribute__((ext_vector_type(8))) __bf16 bf16x8;
typedef __attribute__((ext_vector_type(4))) float f32x4;

#define BM 128
#define BN 128
#define BKB 128   // K-bytes per tile (i8): 128 i8 = 8 x 16B chunks per row
#define GROUP_M 16

__device__ __forceinline__ unsigned bf16_rne(float f) {
  unsigned u = __float_as_uint(f);
  unsigned r = 0x7FFFu + ((u >> 16) & 1u);
  return ((u + r) >> 16) & 0xFFFFu;
}
__device__ __forceinline__ unsigned pack2(float a, float b) {
  return bf16_rne(a) | (bf16_rne(b) << 16);
}
__device__ __forceinline__ int pack4i8(int a, int b, int c, int d) {
  return (a & 0xFF) | ((b & 0xFF) << 8) | ((c & 0xFF) << 16) | (d << 24);
}
__device__ __forceinline__ int q_clamp(float v) {
  int i = __float2int_rn(v);
  return i < -127 ? -127 : (i > 127 ? 127 : i);
}

// ---------------- Phase 1 (merged): per-row int8 quantization ----------------
// blocks [0, M)      : quantize x row -> int8 + xscale[row]
// blocks [M, M+N)    : dequant W row (exact) -> row max -> int8 + wscale[row]
// One block per row, 256 threads x 16 elems (K = 4096).
__global__ __launch_bounds__(256) void prep_kernel(
    const float* __restrict__ x, char* __restrict__ xq, float* __restrict__ xscale,
    int M,
    const int* __restrict__ q, const float* __restrict__ scale,
    const int* __restrict__ zp, char* __restrict__ wq, float* __restrict__ wscale,
    int K, int G) {
  __shared__ float red[4];
  const int b = blockIdx.x;
  const int tid = threadIdx.x;
  float f[16];

  if (b < M) {
    const float4* src = (const float4*)(x + (size_t)b * K) + tid * 4;
    float4 v0 = src[0], v1 = src[1], v2 = src[2], v3 = src[3];
    f[0]=v0.x; f[1]=v0.y; f[2]=v0.z; f[3]=v0.w;
    f[4]=v1.x; f[5]=v1.y; f[6]=v1.z; f[7]=v1.w;
    f[8]=v2.x; f[9]=v2.y; f[10]=v2.z; f[11]=v2.w;
    f[12]=v3.x; f[13]=v3.y; f[14]=v3.z; f[15]=v3.w;
  } else {
    const int row = b - M;
    const int col = tid * 16;
    const int g = col >> 7;  // GROUP_SIZE=128; 16 elems never straddle a group
    const float s = scale[(size_t)row * G + g];
    const float z = (float)zp[(size_t)row * G + g];
    const int4* src = (const int4*)(q + (size_t)row * K + col);
    int4 q0 = src[0], q1 = src[1], q2 = src[2], q3 = src[3];
    const int qs[16] = {q0.x,q0.y,q0.z,q0.w, q1.x,q1.y,q1.z,q1.w,
                        q2.x,q2.y,q2.z,q2.w, q3.x,q3.y,q3.z,q3.w};
#pragma unroll
    for (int j = 0; j < 16; ++j) f[j] = ((float)qs[j] - z) * s;
  }

  float m = 0.f;
#pragma unroll
  for (int j = 0; j < 16; ++j) m = fmaxf(m, fabsf(f[j]));
#pragma unroll
  for (int off = 32; off >= 1; off >>= 1) m = fmaxf(m, __shfl_xor(m, off));
  if ((tid & 63) == 0) red[tid >> 6] = m;
  __syncthreads();
  m = fmaxf(fmaxf(red[0], red[1]), fmaxf(red[2], red[3]));

  const float inv = m > 0.f ? 127.0f / m : 0.f;
  int4 p;
  p.x = pack4i8(q_clamp(f[0]*inv),  q_clamp(f[1]*inv),  q_clamp(f[2]*inv),  q_clamp(f[3]*inv));
  p.y = pack4i8(q_clamp(f[4]*inv),  q_clamp(f[5]*inv),  q_clamp(f[6]*inv),  q_clamp(f[7]*inv));
  p.z = pack4i8(q_clamp(f[8]*inv),  q_clamp(f[9]*inv),  q_clamp(f[10]*inv), q_clamp(f[11]*inv));
  p.w = pack4i8(q_clamp(f[12]*inv), q_clamp(f[13]*inv), q_clamp(f[14]*inv), q_clamp(f[15]*inv));

  if (b < M) {
    ((int4*)(xq + (size_t)b * K))[tid] = p;
    if (tid == 0) xscale[b] = m * (1.0f / 127.0f);
  } else {
    const int row = b - M;
    ((int4*)(wq + (size_t)row * K))[tid] = p;
    if (tid == 0) wscale[row] = m * (1.0f / 127.0f);
  }
}

// ---------------- Phase 2: i8 GEMM (m97 structure, BK=128 bytes) -------------
typedef __attribute__((address_space(1))) void gas_void;
typedef __attribute__((address_space(3))) void las_void;

__device__ __forceinline__ void load_lds16(const void* g, void* l) {
  __builtin_amdgcn_global_load_lds((gas_void*)g, (las_void*)l, 16, 0, 0);
}

// LDS layout identical to R1/R2 bf16 kernel (verified 0 bank conflicts):
// 16B chunk (row r, kq in [0,8)) at slot r*8 + (kq ^ (r&7)).
// Fragment read (i8 16x16x64): lane holds A[m=lane&15][k = quad*16 + j],
// j in [0,16) -> one ds_read_b128 of chunk kq = ks*4 + quad.
__global__ __launch_bounds__(256) void gemm_i8_kernel(
    const char* __restrict__ A,     // [M][K] i8
    const char* __restrict__ Bw,    // [N][K] i8
    const float* __restrict__ ascale,  // [M]
    const float* __restrict__ bscale,  // [N]
    const float* __restrict__ bias,    // [N]
    float* __restrict__ C,             // [M][N] fp32
    int M, int N, int K) {
  __shared__ __align__(16) char Alds[BM * BKB];
  __shared__ __align__(16) char Blds[BN * BKB];
  const int tid  = threadIdx.x;
  const int wave = tid >> 6;
  const int lane = tid & 63;
  const int quad = lane >> 4;
  const int l16  = lane & 15;

  // Grouped-m swizzle (R2: FETCH 1.46->0.79 GB, near per-XCD volume-optimal).
  const int nbm = M / BM;
  const int nbn = N / BN;
  int flat = blockIdx.x;
  int per_group = GROUP_M * nbn;
  int gid = flat / per_group;
  int rem = flat - gid * per_group;
  int gm = nbm - gid * GROUP_M;
  if (gm > GROUP_M) gm = GROUP_M;
  const int bm = (gid * GROUP_M + (rem % gm)) * BM;
  const int bn = (rem / gm) * BN;

  const int wm = (wave & 1) * 64;
  const int wn = (wave >> 1) * 64;

  i32x4 acc[4][4];
#pragma unroll
  for (int i = 0; i < 4; ++i)
#pragma unroll
    for (int j = 0; j < 4; ++j)
      acc[i][j] = (i32x4){0, 0, 0, 0};

  for (int kt = 0; kt < K; kt += BKB) {
#pragma unroll
    for (int t = 0; t < 4; ++t) {
      int s0 = (wave * 4 + t) * 64;   // wave-uniform LDS slot base
      int s  = s0 + lane;
      int m  = s >> 3;
      int kq = (s & 7) ^ (m & 7);
      load_lds16(A  + (size_t)(bm + m) * K + kt + kq * 16, &Alds[s0 * 16]);
      load_lds16(Bw + (size_t)(bn + m) * K + kt + kq * 16, &Blds[s0 * 16]);
    }
    __syncthreads();

#pragma unroll
    for (int ks = 0; ks < 2; ++ks) {
      i32x4 af[4], bfr[4];
#pragma unroll
      for (int tm = 0; tm < 4; ++tm) {
        int m  = wm + tm * 16 + l16;
        int kq = ks * 4 + quad;
        af[tm] = *(const i32x4*)&Alds[(m * 8 + (kq ^ (m & 7))) * 16];
      }
#pragma unroll
      for (int tn = 0; tn < 4; ++tn) {
        int n  = wn + tn * 16 + l16;
        int kq = ks * 4 + quad;
        bfr[tn] = *(const i32x4*)&Blds[(n * 8 + (kq ^ (n & 7))) * 16];
      }
#pragma unroll
      for (int tm = 0; tm < 4; ++tm)
#pragma unroll
        for (int tn = 0; tn < 4; ++tn)
          acc[tm][tn] = __builtin_amdgcn_mfma_i32_16x16x64_i8(
              af[tm], bfr[tn], acc[tm][tn], 0, 0, 0);
    }
    __syncthreads();
  }

  // Epilogue: D row = quad*4 + v, col = lane&15 (shape-determined, m121-128).
  // C = ascale[m] * bscale[n] * idot + bias[n]; nontemporal (write-once C).
#pragma unroll
  for (int tn = 0; tn < 4; ++tn) {
    int col = bn + wn + tn * 16 + l16;
    float bv = bias[col];
    float ws = bscale[col];
#pragma unroll
    for (int tm = 0; tm < 4; ++tm) {
      int row0 = bm + wm + tm * 16 + quad * 4;
#pragma unroll
      for (int v = 0; v < 4; ++v) {
        float val = ascale[row0 + v] * ws * (float)acc[tm][tn][v] + bv;
        __builtin_nontemporal_store(val, &C[(size_t)(row0 + v) * N + col]);
      }
    }
  }
}

// ---------------- Fallback: fused bf16 dequant GEMM (known-correct, R1) ------
__global__ __launch_bounds__(256) void gemm_fused_kernel(
    const float* __restrict__ X, const int* __restrict__ Q,
    const float* __restrict__ scale, const int* __restrict__ zp,
    const float* __restrict__ bias, float* __restrict__ C,
    int M, int N, int K, int G) {
  __shared__ __align__(16) bf16 Alds[128 * 64];
  __shared__ __align__(16) bf16 Blds[128 * 64];
  const int tid  = threadIdx.x;
  const int wave = tid >> 6;
  const int lane = tid & 63;
  const int quad = lane >> 4;
  const int l16  = lane & 15;
  const int bm = blockIdx.y * 128;
  const int bn = blockIdx.x * 128;
  const int wm = (wave & 1) * 64;
  const int wn = (wave >> 1) * 64;

  f32x4 acc[4][4];
#pragma unroll
  for (int i = 0; i < 4; ++i)
#pragma unroll
    for (int j = 0; j < 4; ++j)
      acc[i][j] = (f32x4){0.f, 0.f, 0.f, 0.f};

  for (int kt = 0; kt < K; kt += 64) {
#pragma unroll
    for (int i = 0; i < 4; ++i) {
      int c = tid + i * 256;
      int m = c >> 3;
      int kq = (c & 7) ^ (m & 7);
      const float* src = X + (size_t)(bm + m) * K + kt + kq * 8;
      float4 v0 = *(const float4*)src;
      float4 v1 = *(const float4*)(src + 4);
      uint4 p;
      p.x = pack2(v0.x, v0.y); p.y = pack2(v0.z, v0.w);
      p.z = pack2(v1.x, v1.y); p.w = pack2(v1.z, v1.w);
      *(uint4*)&Alds[c * 8] = p;
    }
#pragma unroll
    for (int i = 0; i < 4; ++i) {
      int c = tid + i * 256;
      int n = c >> 3;
      int kq = (c & 7) ^ (n & 7);
      int kcol = kt + kq * 8;
      size_t row = (size_t)(bn + n);
      int g = kcol >> 7;
      float s = scale[row * G + g];
      float z = (float)zp[row * G + g];
      const int* src = Q + row * K + kcol;
      int4 q0 = *(const int4*)src;
      int4 q1 = *(const int4*)(src + 4);
      uint4 p;
      p.x = pack2(((float)q0.x - z) * s, ((float)q0.y - z) * s);
      p.y = pack2(((float)q0.z - z) * s, ((float)q0.w - z) * s);
      p.z = pack2(((float)q1.x - z) * s, ((float)q1.y - z) * s);
      p.w = pack2(((float)q1.z - z) * s, ((float)q1.w - z) * s);
      *(uint4*)&Blds[c * 8] = p;
    }
    __syncthreads();

#pragma unroll
    for (int ks = 0; ks < 2; ++ks) {
      bf16x8 af[4], bfr[4];
#pragma unroll
      for (int tm = 0; tm < 4; ++tm) {
        int m  = wm + tm * 16 + l16;
        int kq = ks * 4 + quad;
        af[tm] = *(const bf16x8*)&Alds[(m * 8 + (kq ^ (m & 7))) * 8];
      }
#pragma unroll
      for (int tn = 0; tn < 4; ++tn) {
        int n  = wn + tn * 16 + l16;
        int kq = ks * 4 + quad;
        bfr[tn] = *(const bf16x8*)&Blds[(n * 8 + (kq ^ (n & 7))) * 8];
      }
#pragma unroll
      for (int tm = 0; tm < 4; ++tm)
#pragma unroll
        for (int tn = 0; tn < 4; ++tn)
          acc[tm][tn] = __builtin_amdgcn_mfma_f32_16x16x32_bf16(
              af[tm], bfr[tn], acc[tm][tn], 0, 0, 0);
    }
    __syncthreads();
  }

#pragma unroll
  for (int tn = 0; tn < 4; ++tn) {
    int col = bn + wn + tn * 16 + l16;
    float bv = bias[col];
#pragma unroll
    for (int tm = 0; tm < 4; ++tm) {
      int row0 = bm + wm + tm * 16 + quad * 4;
#pragma unroll
      for (int v = 0; v < 4; ++v)
        C[(size_t)(row0 + v) * N + col] = acc[tm][tn][v] + bv;
    }
  }
}

extern "C" void kernel_launch(void* const* d_in, const int* in_sizes, int n_in,
                              void* d_out, int out_size, void* d_ws, size_t ws_size,
                              hipStream_t stream) {
  const float* x     = (const float*)d_in[0];
  const int*   qw    = (const int*)d_in[1];
  const float* scale = (const float*)d_in[2];
  const int*   zp    = (const int*)d_in[3];
  const float* bias  = (const float*)d_in[4];
  float* out = (float*)d_out;

  const int O = in_sizes[4];                 // 11008
  const int I = (int)(in_sizes[1] / O);      // 4096
  const int M = (int)(in_sizes[0] / I);      // 4096 (= B*S)
  const int G = in_sizes[2] / O;             // 32
  const int K = I, N = O;

  // ws layout: xq[M*K] i8 | xscale[M] f32 | wq[N*K] i8 | wscale[N] f32
  size_t off_xq = 0;
  size_t off_xs = off_xq + (size_t)M * K;
  size_t off_wq = (off_xs + (size_t)M * 4 + 255) & ~(size_t)255;
  size_t off_ws_ = off_wq + (size_t)N * K;
  size_t need   = ((off_ws_ + (size_t)N * 4 + 255) & ~(size_t)255);

  if (ws_size >= need && (K % 4096) == 0) {
    char*  xq = (char*)d_ws + off_xq;
    float* xs = (float*)((char*)d_ws + off_xs);
    char*  wq = (char*)d_ws + off_wq;
    float* wsc = (float*)((char*)d_ws + off_ws_);

    prep_kernel<<<M + N, 256, 0, stream>>>(x, xq, xs, M, qw, scale, zp, wq, wsc, K, G);

    int nblocks = (M / BM) * (N / BN);
    gemm_i8_kernel<<<nblocks, 256, 0, stream>>>(xq, wq, xs, wsc, bias, out, M, N, K);
  } else {
    dim3 gemm_grid((unsigned)(N / 128), (unsigned)(M / 128));
    gemm_fused_kernel<<<gemm_grid, 256, 0, stream>>>(x, qw, scale, zp, bias, out,
                                                     M, N, K, G);
  }
}